// Round 10
// baseline (568.282 us; speedup 1.0000x reference)
//
#include <hip/hip_runtime.h>
#include <math.h>

#define B_      64
#define N_      128
#define S_      2048
#define D_      128
#define K_TOP   128
#define CAPB    1024     // per-block candidate cap
#define LISTCAP 7424     // fan-in select list cap (fits 32 KiB LDS with hist)

typedef _Float16 f16x8 __attribute__((ext_vector_type(8)));
typedef float    f32x4 __attribute__((ext_vector_type(4)));

union Frag { uint4 u; f16x8 h; };

__device__ __forceinline__ unsigned fkey(float x) {
    unsigned u = __float_as_uint(x);
    return (u & 0x80000000u) ? ~u : (u | 0x80000000u);
}
__device__ __forceinline__ float unkey(unsigned k) {
    unsigned u = (k & 0x80000000u) ? (k & 0x7fffffffu) : ~k;
    return __uint_as_float(u);
}

// 8 fp32 -> 8 fp16 (RNE) packed into uint4
__device__ __forceinline__ uint4 cvt8h(float4 a, float4 b) {
    union { _Float16 h[8]; uint4 u; } r;
    r.h[0] = (_Float16)a.x; r.h[1] = (_Float16)a.y;
    r.h[2] = (_Float16)a.z; r.h[3] = (_Float16)a.w;
    r.h[4] = (_Float16)b.x; r.h[5] = (_Float16)b.y;
    r.h[6] = (_Float16)b.z; r.h[7] = (_Float16)b.w;
    return r.u;
}

// K1: fp16 MFMA GEMM (128x128 tile, K=128) + R6 epilogue + device-side fan-in:
// the 16th-finishing block per z performs the exact top-128 selection inline.
__global__ __launch_bounds__(256) void gemm_fused(
    const float* __restrict__ q, const float* __restrict__ dpos,
    const float* __restrict__ dneg, int nb, int b0,
    unsigned* __restrict__ rowmaxG,   // [2nb*N_], zeroed
    unsigned* __restrict__ cand,      // [2nb*16*CAPB]
    unsigned* __restrict__ candCnt,   // [2nb*16]
    unsigned* __restrict__ done,      // [2nb], zeroed
    float*    __restrict__ sc)        // [2*B_]
{
    __shared__ uint4 sh4[2048];       // 32 KiB; everything aliases into here
    unsigned* sw = (unsigned*)sh4;
    unsigned* scanS = sw + 4096;      // 256
    unsigned* rmx   = sw + 5376;      // 128
    unsigned* ctrl  = sw + 5504;      // 2
    unsigned* flagp = sw + 8190;      // fan-in flag

    const int z  = blockIdx.z;
    const int bz = (z < nb) ? z : z - nb;
    const float* docs = (z < nb) ? dpos : dneg;
    const int bx = blockIdx.x;
    const int s0 = bx * 128;
    const float* qb = q + (size_t)(b0 + bz) * N_ * D_;
    const float* db = docs + (size_t)(b0 + bz) * S_ * D_;

    const int t    = threadIdx.x;
    const int lane = t & 63;
    const int w    = t >> 6;
    const int quad = lane >> 4;
    const int m    = lane & 15;
    const int Ibase = (w >> 1) << 2;
    const int Jbase = (w & 1) << 2;

    f32x4 acc[4][4];
    #pragma unroll
    for (int i = 0; i < 4; ++i)
        #pragma unroll
        for (int j = 0; j < 4; ++j)
            acc[i][j] = f32x4{0.f, 0.f, 0.f, 0.f};

    for (int k0 = 0; k0 < D_; k0 += 64) {
        #pragma unroll
        for (int p = 0; p < 4; ++p) {
            int ci  = t + (p << 8);
            int row = ((ci >> 7) << 4) | (ci & 15);
            int kf  = k0 + (((ci >> 4) & 7) << 3);
            const float* ga = qb + (size_t)row * D_ + kf;
            sh4[ci] = cvt8h(*(const float4*)ga, *(const float4*)(ga + 4));
            const float* gb = db + (size_t)(s0 + row) * D_ + kf;
            sh4[1024 + ci] = cvt8h(*(const float4*)gb, *(const float4*)(gb + 4));
        }
        __syncthreads();
        #pragma unroll
        for (int ks = 0; ks < 2; ++ks) {
            Frag af[4], bf[4];
            #pragma unroll
            for (int i = 0; i < 4; ++i) {
                af[i].u = sh4[(Ibase + i) * 128 + ks * 64 + lane];
                bf[i].u = sh4[1024 + (Jbase + i) * 128 + ks * 64 + lane];
            }
            #pragma unroll
            for (int i = 0; i < 4; ++i)
                #pragma unroll
                for (int j = 0; j < 4; ++j)
                    acc[i][j] = __builtin_amdgcn_mfma_f32_16x16x32_f16(
                        af[i].h, bf[j].h, acc[i][j], 0, 0, 0);
        }
        __syncthreads();
    }

    // ---- R6-form epilogue ----
    {
        const uint4 zz = uint4{0u, 0u, 0u, 0u};
        sh4[t] = zz; sh4[t + 256] = zz; sh4[t + 512] = zz; sh4[t + 768] = zz;
    }
    if (t < 128) rmx[t] = 0u;
    if (t == 0) { ctrl[0] = 0u; ctrl[1] = 0u; }
    __syncthreads();

    const unsigned rep = t & 1;
    #pragma unroll
    for (int i = 0; i < 4; ++i) {
        #pragma unroll
        for (int r = 0; r < 4; ++r) {
            int row = ((Ibase + i) << 4) + (quad << 2) + r;
            unsigned km = max(max(fkey(acc[i][0][r]), fkey(acc[i][1][r])),
                              max(fkey(acc[i][2][r]), fkey(acc[i][3][r])));
            #pragma unroll
            for (int off = 1; off < 16; off <<= 1)
                km = max(km, (unsigned)__shfl_xor((int)km, off, 64));
            if (m == 0) atomicMax(&rmx[row], km);
            #pragma unroll
            for (int j = 0; j < 4; ++j)
                atomicAdd(&sw[((fkey(acc[i][j][r]) >> 21) << 1) | rep], 1u);
        }
    }
    __syncthreads();

    {   // chunk sums (thread t: bins 8t..8t+7)
        unsigned s = 0;
        #pragma unroll
        for (int j = 0; j < 8; ++j) {
            int bin = (t << 3) + j;
            s += sw[bin * 2] + sw[bin * 2 + 1];
        }
        scanS[t] = s;
    }
    __syncthreads();
    #pragma unroll
    for (int d = 1; d < 256; d <<= 1) {   // Hillis-Steele suffix scan
        unsigned v = scanS[t] + ((t + d < 256) ? scanS[t + d] : 0u);
        __syncthreads();
        scanS[t] = v;
        __syncthreads();
    }
    {
        unsigned Sme = scanS[t];
        unsigned Snx = (t == 255) ? 0u : scanS[t + 1];
        if (Sme >= K_TOP && Snx < K_TOP) {
            unsigned cum = Snx;
            unsigned lbv = (unsigned)(t * 8);
            for (int bin = t * 8 + 7; bin >= t * 8; --bin) {
                unsigned hh = sw[bin * 2] + sw[bin * 2 + 1];
                if (cum + hh >= K_TOP) { lbv = (unsigned)bin; break; }
                cum += hh;
            }
            ctrl[0] = lbv;
        }
    }
    __syncthreads();
    const unsigned lb = ctrl[0];

    unsigned* buf = sw;    // hist dead
    #pragma unroll
    for (int i = 0; i < 4; ++i)
        #pragma unroll
        for (int j = 0; j < 4; ++j)
            #pragma unroll
            for (int r = 0; r < 4; ++r) {
                unsigned u = fkey(acc[i][j][r]);
                if ((u >> 21) >= lb) {
                    unsigned idx = atomicAdd(&ctrl[1], 1u);
                    if (idx < CAPB) buf[idx] = u;
                }
            }
    __syncthreads();
    const int slot = z * 16 + bx;
    unsigned c = min(ctrl[1], (unsigned)CAPB);
    for (unsigned i = t; i < c; i += 256) cand[(size_t)slot * CAPB + i] = buf[i];
    if (t == 0) candCnt[slot] = c;
    if (t < 128) atomicMax(&rowmaxG[z * N_ + t], rmx[t]);

    // ---- fan-in: last block of this z performs the selection ----
    __threadfence();                                    // release
    if (t == 0) flagp[0] = (atomicAdd(&done[z], 1u) == 15u) ? 1u : 0u;
    __syncthreads();
    if (!flagp[0]) return;
    __threadfence();                                    // acquire

    unsigned* list = sw;                 // [0, LISTCAP)
    unsigned* h    = sw + LISTCAP;       // 512 (256 bins x 2 replicas)
    unsigned* cns  = h + 512;            // 16
    unsigned* offs = cns + 16;           // 17
    unsigned* ct   = offs + 17;          // pref, krem
    float*    fs   = (float*)(ct + 2);   // 8 floats

    if (t < 16) cns[t] = candCnt[z * 16 + t];
    __syncthreads();
    if (t <= 16) {
        unsigned o = 0;
        for (int s = 0; s < t; ++s) o += cns[s];
        offs[t] = min(o, (unsigned)LISTCAP);
    }
    if (t == 0) { ct[0] = 0u; ct[1] = K_TOP; }
    __syncthreads();
    for (int s = w; s < 16; s += 4) {          // wave-parallel gather
        unsigned base = offs[s];
        unsigned cnt  = offs[s + 1] - base;
        const unsigned* src = cand + (size_t)(z * 16 + s) * CAPB;
        for (unsigned i = lane; i < cnt; i += 64) list[base + i] = src[i];
    }
    __syncthreads();
    const int total = (int)offs[16];

    for (int r = 0; r < 4; ++r) {
        const int shift = 24 - 8 * r;
        h[t] = 0u; h[t + 256] = 0u;
        __syncthreads();
        const unsigned pref = ct[0];
        const unsigned k = ct[1];
        for (int i = t; i < total; i += 256) {
            unsigned u = list[i];
            bool ok = (r == 0) || ((u >> (shift + 8)) == (pref >> (shift + 8)));
            if (ok) atomicAdd(&h[(((u >> shift) & 255u) << 1) | rep], 1u);
        }
        __syncthreads();
        if (w == 0) {
            unsigned cs4[4]; unsigned tot = 0;
            #pragma unroll
            for (int j = 0; j < 4; ++j) {
                int bin = (lane << 2) + j;
                cs4[j] = h[bin * 2] + h[bin * 2 + 1];
                tot += cs4[j];
            }
            unsigned suf = tot;
            #pragma unroll
            for (int off = 1; off < 64; off <<= 1) {
                unsigned o = (unsigned)__shfl_down((int)suf, off, 64);
                suf += (lane + off < 64) ? o : 0u;
            }
            unsigned Snx = (unsigned)__shfl_down((int)suf, 1, 64);
            if (lane == 63) Snx = 0u;
            if (suf >= k && Snx < k) {
                unsigned cum = Snx;
                for (int j = 3; j >= 0; --j) {
                    if (cum + cs4[j] < k) { cum += cs4[j]; continue; }
                    ct[0] = pref | ((unsigned)((lane << 2) + j) << shift);
                    ct[1] = k - cum;
                    break;
                }
            }
        }
        __syncthreads();
    }
    const unsigned T = ct[0];

    float v = 0.f, cc = 0.f;
    if (t < N_) {
        unsigned km = rowmaxG[z * N_ + t];
        if (km >= T) { v = fmaxf(unkey(km), 0.f); cc = 1.f; }
    }
    #pragma unroll
    for (int off = 32; off > 0; off >>= 1) {
        v  += __shfl_xor(v, off, 64);
        cc += __shfl_xor(cc, off, 64);
    }
    if (lane == 0) { fs[w] = v; fs[4 + w] = cc; }
    __syncthreads();
    if (t == 0) {
        float Sv = fs[0] + fs[1] + fs[2] + fs[3];
        float Cv = fs[4] + fs[5] + fs[6] + fs[7];
        int b = b0 + bz;
        int side = (z < nb) ? 0 : 1;
        sc[side * B_ + b] = Sv / fmaxf(Cv, 0.001f);
    }
}

// K2: loss = mean_b softplus(neg - pos)
__global__ __launch_bounds__(64) void final_loss(
    const float* __restrict__ sc, float* __restrict__ out)
{
    int b = threadIdx.x;
    float x = sc[B_ + b] - sc[b];
    float sp = (x > 20.f) ? x : log1pf(expf(x));
    #pragma unroll
    for (int o = 32; o > 0; o >>= 1) sp += __shfl_xor(sp, o, 64);
    if (b == 0) out[0] = sp * (1.f / B_);
}

extern "C" void kernel_launch(void* const* d_in, const int* in_sizes, int n_in,
                              void* d_out, int out_size, void* d_ws, size_t ws_size,
                              hipStream_t stream) {
    const float* q    = (const float*)d_in[0];
    const float* dpos = (const float*)d_in[1];
    const float* dneg = (const float*)d_in[2];
    float* out = (float*)d_out;
    char* ws = (char*)d_ws;

    // per-batch words (x2 sides): done 1 + rowmax 128 + candCnt 16 + cand 16*CAPB
    const size_t per_batch = 2ull * (1 + N_ + 16 + 16 * CAPB) * 4;
    const size_t fixed = 2 * B_ * sizeof(float) + 256;
    size_t avail = (ws_size > fixed) ? (ws_size - fixed) : 0;
    int Bc = (int)(avail / per_batch);
    if (Bc > B_) Bc = B_;
    if (Bc < 1) Bc = 1;

    char* p = ws;
    float*    sc      = (float*)p;    p += ((2 * B_ * 4 + 255) / 256) * 256;
    unsigned* done    = (unsigned*)p;                   // zero region start
    unsigned* rowmaxG = done + (size_t)2 * Bc;
    p += ((size_t)2 * Bc * (1 + N_) * 4 + 255) / 256 * 256;
    unsigned* candCnt = (unsigned*)p; p += (size_t)2 * Bc * 16 * 4;
    unsigned* cand    = (unsigned*)p; p += (size_t)2 * Bc * 16 * CAPB * 4;

    const size_t zbytes = (size_t)2 * Bc * (1 + N_) * 4;

    for (int b0 = 0; b0 < B_; b0 += Bc) {
        int nb = (B_ - b0 < Bc) ? (B_ - b0) : Bc;
        (void)hipMemsetAsync(done, 0, zbytes, stream);
        gemm_fused<<<dim3(S_ / 128, 1, 2 * nb), 256, 0, stream>>>(
            q, dpos, dneg, nb, b0, rowmaxG, cand, candCnt, done, sc);
    }
    final_loss<<<1, 64, 0, stream>>>(sc, out);
}

// Round 11
// 257.822 us; speedup vs baseline: 2.2042x; 2.2042x over previous
//
#include <hip/hip_runtime.h>
#include <math.h>

#define B_      64
#define N_      128
#define S_      2048
#define D_      128
#define K_TOP   128
#define CAPB    1024     // per-block candidate cap
#define LISTCAP 8192     // per-(batch,side) candidate list cap in select

typedef _Float16 f16x8 __attribute__((ext_vector_type(8)));
typedef float    f32x4 __attribute__((ext_vector_type(4)));

union Frag { uint4 u; f16x8 h; };

// Monotone mapping: float total order -> unsigned total order
__device__ __forceinline__ unsigned fkey(float x) {
    unsigned u = __float_as_uint(x);
    return (u & 0x80000000u) ? ~u : (u | 0x80000000u);
}
__device__ __forceinline__ float unkey(unsigned k) {
    unsigned u = (k & 0x80000000u) ? (k & 0x7fffffffu) : ~k;
    return __uint_as_float(u);
}

// 8 fp32 -> 8 fp16 (RNE) packed into uint4
__device__ __forceinline__ uint4 cvt8h(float4 a, float4 b) {
    union { _Float16 h[8]; uint4 u; } r;
    r.h[0] = (_Float16)a.x; r.h[1] = (_Float16)a.y;
    r.h[2] = (_Float16)a.z; r.h[3] = (_Float16)a.w;
    r.h[4] = (_Float16)b.x; r.h[5] = (_Float16)b.y;
    r.h[6] = (_Float16)b.z; r.h[7] = (_Float16)b.w;
    return r.u;
}

// K1: fp16 MFMA GEMM (128x128 tile, K=128, BK=64) — VERBATIM R6 form
// (measured 75.7 us, VGPR 80). Epilogues in-register: per-row max and local
// top-128 candidate extraction (2048-bin hist + parallel suffix scan).
// Plain global stores only; visibility via kernel boundary (NO fences).
__global__ __launch_bounds__(256) void gemm_fused(
    const float* __restrict__ q, const float* __restrict__ dpos,
    const float* __restrict__ dneg, int nb, int b0,
    unsigned* __restrict__ rowmaxLocal,   // [2nb*16*N_]
    unsigned* __restrict__ cand,          // [2nb*16*CAPB]
    unsigned* __restrict__ candCnt)       // [2nb*16]
{
    __shared__ uint4 sh4[2048];           // 32 KiB
    unsigned* sw = (unsigned*)sh4;
    unsigned* scanS = sw + 4096;          // 256
    unsigned* rmx   = sw + 5376;          // 128
    unsigned* ctrl  = sw + 5504;          // 2

    const int z  = blockIdx.z;
    const int bz = (z < nb) ? z : z - nb;
    const float* docs = (z < nb) ? dpos : dneg;
    const int bx = blockIdx.x;
    const int s0 = bx * 128;
    const float* qb = q + (size_t)(b0 + bz) * N_ * D_;
    const float* db = docs + (size_t)(b0 + bz) * S_ * D_;

    const int t    = threadIdx.x;
    const int lane = t & 63;
    const int w    = t >> 6;
    const int quad = lane >> 4;
    const int m    = lane & 15;
    const int Ibase = (w >> 1) << 2;
    const int Jbase = (w & 1) << 2;

    f32x4 acc[4][4];
    #pragma unroll
    for (int i = 0; i < 4; ++i)
        #pragma unroll
        for (int j = 0; j < 4; ++j)
            acc[i][j] = f32x4{0.f, 0.f, 0.f, 0.f};

    for (int k0 = 0; k0 < D_; k0 += 64) {
        #pragma unroll
        for (int p = 0; p < 4; ++p) {
            int ci  = t + (p << 8);
            int row = ((ci >> 7) << 4) | (ci & 15);
            int kf  = k0 + (((ci >> 4) & 7) << 3);
            const float* ga = qb + (size_t)row * D_ + kf;
            sh4[ci] = cvt8h(*(const float4*)ga, *(const float4*)(ga + 4));
            const float* gb = db + (size_t)(s0 + row) * D_ + kf;
            sh4[1024 + ci] = cvt8h(*(const float4*)gb, *(const float4*)(gb + 4));
        }
        __syncthreads();
        #pragma unroll
        for (int ks = 0; ks < 2; ++ks) {
            Frag af[4], bf[4];
            #pragma unroll
            for (int i = 0; i < 4; ++i) {
                af[i].u = sh4[(Ibase + i) * 128 + ks * 64 + lane];
                bf[i].u = sh4[1024 + (Jbase + i) * 128 + ks * 64 + lane];
            }
            #pragma unroll
            for (int i = 0; i < 4; ++i)
                #pragma unroll
                for (int j = 0; j < 4; ++j)
                    acc[i][j] = __builtin_amdgcn_mfma_f32_16x16x32_f16(
                        af[i].h, bf[j].h, acc[i][j], 0, 0, 0);
        }
        __syncthreads();
    }

    // ---- epilogue (R6 form) ----
    for (int i = t; i < 4096; i += 256) sw[i] = 0u;
    if (t < 128) rmx[t] = 0u;
    if (t == 0) { ctrl[0] = 0u; ctrl[1] = 0u; }
    __syncthreads();

    const unsigned rep = t & 1;
    #pragma unroll
    for (int i = 0; i < 4; ++i) {
        #pragma unroll
        for (int r = 0; r < 4; ++r) {
            int row = ((Ibase + i) << 4) + (quad << 2) + r;
            unsigned km = max(max(fkey(acc[i][0][r]), fkey(acc[i][1][r])),
                              max(fkey(acc[i][2][r]), fkey(acc[i][3][r])));
            #pragma unroll
            for (int off = 1; off < 16; off <<= 1)
                km = max(km, (unsigned)__shfl_xor((int)km, off, 64));
            if (m == 0) atomicMax(&rmx[row], km);
            #pragma unroll
            for (int j = 0; j < 4; ++j)
                atomicAdd(&sw[((fkey(acc[i][j][r]) >> 21) << 1) | rep], 1u);
        }
    }
    __syncthreads();

    {   // chunk sums: thread t covers bins [8t, 8t+8)
        unsigned s = 0;
        #pragma unroll
        for (int j = 0; j < 8; ++j) {
            int bin = (t << 3) + j;
            s += sw[bin * 2] + sw[bin * 2 + 1];
        }
        scanS[t] = s;
    }
    __syncthreads();
    #pragma unroll
    for (int d = 1; d < 256; d <<= 1) {   // Hillis-Steele suffix scan
        unsigned v = scanS[t] + ((t + d < 256) ? scanS[t + d] : 0u);
        __syncthreads();
        scanS[t] = v;
        __syncthreads();
    }
    {
        unsigned Sme = scanS[t];
        unsigned Snx = (t == 255) ? 0u : scanS[t + 1];
        if (Sme >= K_TOP && Snx < K_TOP) {
            unsigned cum = Snx;
            unsigned lbv = (unsigned)(t * 8);
            for (int bin = t * 8 + 7; bin >= t * 8; --bin) {
                unsigned hh = sw[bin * 2] + sw[bin * 2 + 1];
                if (cum + hh >= K_TOP) { lbv = (unsigned)bin; break; }
                cum += hh;
            }
            ctrl[0] = lbv;
        }
    }
    __syncthreads();
    const unsigned lb = ctrl[0];

    unsigned* buf = sw;    // hist dead; reuse as buffer
    #pragma unroll
    for (int i = 0; i < 4; ++i)
        #pragma unroll
        for (int j = 0; j < 4; ++j)
            #pragma unroll
            for (int r = 0; r < 4; ++r) {
                unsigned u = fkey(acc[i][j][r]);
                if ((u >> 21) >= lb) {
                    unsigned idx = atomicAdd(&ctrl[1], 1u);
                    if (idx < CAPB) buf[idx] = u;
                }
            }
    __syncthreads();
    const int slot = z * 16 + bx;
    unsigned c = min(ctrl[1], (unsigned)CAPB);
    for (unsigned i = t; i < c; i += 256) cand[(size_t)slot * CAPB + i] = buf[i];
    if (t == 0) candCnt[slot] = c;
    if (t < 128) rowmaxLocal[(size_t)slot * N_ + t] = rmx[t];
}

// K2: one block per batch, BOTH sides. Exact 128th-largest key via 32-step
// greedy bit-build (count >= threshold, shuffle-reduced — no atomics, no hot
// bins). Then per-side score from rowmax, then softplus(neg-pos) -> lossb[b].
__global__ __launch_bounds__(256) void select_loss(
    const unsigned* __restrict__ cand, const unsigned* __restrict__ candCnt,
    const unsigned* __restrict__ rowmaxLocal, float* __restrict__ lossb,
    int nb, int b0)
{
    __shared__ unsigned list[LISTCAP];    // 32 KiB
    __shared__ unsigned cnts[16];
    __shared__ unsigned wsum[8];          // 4 waves x 2 parity
    __shared__ float fs[4], fc[4], sscore[2];
    const int bz   = blockIdx.x;
    const int t    = threadIdx.x;
    const int lane = t & 63;
    const int w    = t >> 6;

    for (int side = 0; side < 2; ++side) {
        const int z = side * nb + bz;
        if (t < 16) cnts[t] = candCnt[z * 16 + t];
        __syncthreads();

        // copy 16 slots into contiguous LDS list (all threads agree on bases)
        unsigned base = 0;
        for (int s = 0; s < 16; ++s) {
            unsigned c   = cnts[s];
            unsigned cap = (c < (unsigned)(LISTCAP)-base) ? c : (unsigned)LISTCAP - base;
            const unsigned* src = cand + (size_t)(z * 16 + s) * CAPB;
            for (unsigned i = t; i < cap; i += 256) list[base + i] = src[i];
            base += cap;
        }
        const int total = (int)base;
        __syncthreads();

        // greedy MSB->LSB: T |= bit if count(list >= T|bit) >= K_TOP.
        // Final T == exact K_TOP-th largest key.
        unsigned T = 0u;
        for (int bit = 31; bit >= 0; --bit) {
            const unsigned cT = T | (1u << bit);
            int cnt = 0;
            for (int i = t; i < total; i += 256)
                cnt += (list[i] >= cT) ? 1 : 0;
            #pragma unroll
            for (int off = 32; off > 0; off >>= 1)
                cnt += __shfl_xor(cnt, off, 64);
            const int par = bit & 1;
            if (lane == 0) wsum[w * 2 + par] = (unsigned)cnt;
            __syncthreads();
            unsigned tot = wsum[par] + wsum[2 + par] + wsum[4 + par] + wsum[6 + par];
            if (tot >= (unsigned)K_TOP) T = cT;
        }

        // score: combine rowmax over 16 slots, threshold at T
        float v = 0.f, c = 0.f;
        if (t < N_) {
            unsigned km = 0u;
            #pragma unroll
            for (int s = 0; s < 16; ++s)
                km = max(km, rowmaxLocal[(size_t)(z * 16 + s) * N_ + t]);
            if (km >= T) { v = fmaxf(unkey(km), 0.f); c = 1.f; }
        }
        #pragma unroll
        for (int off = 32; off > 0; off >>= 1) {
            v += __shfl_xor(v, off, 64);
            c += __shfl_xor(c, off, 64);
        }
        if (lane == 0) { fs[w] = v; fc[w] = c; }
        __syncthreads();
        if (t == 0) {
            float Sv = fs[0] + fs[1];       // rows live in waves 0..1 only
            float Cv = fc[0] + fc[1];
            sscore[side] = Sv / fmaxf(Cv, 0.001f);
        }
        __syncthreads();
    }
    if (t == 0) {
        float x = sscore[1] - sscore[0];
        lossb[b0 + bz] = (x > 20.f) ? x : log1pf(expf(x));
    }
}

// K3: out = mean_b lossb
__global__ __launch_bounds__(64) void final_loss(
    const float* __restrict__ lossb, float* __restrict__ out)
{
    float sp = lossb[threadIdx.x];
    #pragma unroll
    for (int o = 32; o > 0; o >>= 1) sp += __shfl_xor(sp, o, 64);
    if (threadIdx.x == 0) out[0] = sp * (1.f / B_);
}

extern "C" void kernel_launch(void* const* d_in, const int* in_sizes, int n_in,
                              void* d_out, int out_size, void* d_ws, size_t ws_size,
                              hipStream_t stream) {
    const float* q    = (const float*)d_in[0];
    const float* dpos = (const float*)d_in[1];
    const float* dneg = (const float*)d_in[2];
    float* out = (float*)d_out;
    char* ws = (char*)d_ws;

    // per-batch bytes (x2 sides): rowmaxLocal 16*128 + candCnt 16 + cand 16*CAPB
    const size_t per_batch = 2ull * (16 * N_ + 16 + 16 * CAPB) * 4;
    const size_t fixed = B_ * sizeof(float) + 256;
    size_t avail = (ws_size > fixed) ? (ws_size - fixed) : 0;
    int Bc = (int)(avail / per_batch);
    if (Bc > B_) Bc = B_;
    if (Bc < 1) Bc = 1;

    char* p = ws;
    float*    lossb       = (float*)p;    p += ((B_ * 4 + 255) / 256) * 256;
    unsigned* rowmaxLocal = (unsigned*)p; p += (size_t)2 * Bc * 16 * N_ * 4;
    unsigned* candCnt     = (unsigned*)p; p += (size_t)2 * Bc * 16 * 4;
    unsigned* cand        = (unsigned*)p; p += (size_t)2 * Bc * 16 * CAPB * 4;

    for (int b0 = 0; b0 < B_; b0 += Bc) {
        int nb = (B_ - b0 < Bc) ? (B_ - b0) : Bc;
        gemm_fused<<<dim3(S_ / 128, 1, 2 * nb), 256, 0, stream>>>(
            q, dpos, dneg, nb, b0, rowmaxLocal, cand, candCnt);
        select_loss<<<nb, 256, 0, stream>>>(
            cand, candCnt, rowmaxLocal, lossb, nb, b0);
    }
    final_loss<<<1, 64, 0, stream>>>(lossb, out);
}